// Round 13
// baseline (6316.278 us; speedup 1.0000x reference)
//
#include <hip/hip_runtime.h>

#define B_DIM 16
#define S_DIM 4096
#define N_DIM 256
#define EPS 1e-5f

// ---------------------------------------------------------------------------
// Tiled f32 GEMM: Y[M,256] = X[M,256] @ W[256,256]^T + bias   (unchanged)
// ---------------------------------------------------------------------------
__global__ __launch_bounds__(256)
void gemm_xwT_bias(const float* __restrict__ X,
                   const float* __restrict__ W,
                   const float* __restrict__ bias,
                   float* __restrict__ Y,
                   int M)
{
    __shared__ float Xs[16][68];
    __shared__ float Ws[16][68];

    const int tid = threadIdx.x;
    const int m0 = blockIdx.x * 64;
    const int n0 = blockIdx.y * 64;
    const int tx = tid & 15;
    const int ty = tid >> 4;

    float acc[4][4] = {};

    for (int k0 = 0; k0 < 256; k0 += 16) {
        {
            const int r  = tid >> 2;
            const int kk = (tid & 3) * 4;
            float4 v = *(const float4*)(X + (size_t)(m0 + r) * 256 + k0 + kk);
            Xs[kk + 0][r] = v.x; Xs[kk + 1][r] = v.y;
            Xs[kk + 2][r] = v.z; Xs[kk + 3][r] = v.w;
            float4 w = *(const float4*)(W + (size_t)(n0 + r) * 256 + k0 + kk);
            Ws[kk + 0][r] = w.x; Ws[kk + 1][r] = w.y;
            Ws[kk + 2][r] = w.z; Ws[kk + 3][r] = w.w;
        }
        __syncthreads();

        #pragma unroll
        for (int k = 0; k < 16; ++k) {
            float4 xv = *(const float4*)&Xs[k][ty * 4];
            float4 wv = *(const float4*)&Ws[k][tx * 4];
            float xa[4] = {xv.x, xv.y, xv.z, xv.w};
            float wa[4] = {wv.x, wv.y, wv.z, wv.w};
            #pragma unroll
            for (int i = 0; i < 4; ++i)
                #pragma unroll
                for (int j = 0; j < 4; ++j)
                    acc[i][j] += xa[i] * wa[j];
        }
        __syncthreads();
    }

    const int nbase = n0 + tx * 4;
    float4 bv = *(const float4*)(bias + nbase);
    #pragma unroll
    for (int i = 0; i < 4; ++i) {
        const int m = m0 + ty * 4 + i;
        float4 o;
        o.x = acc[i][0] + bv.x;
        o.y = acc[i][1] + bv.y;
        o.z = acc[i][2] + bv.z;
        o.w = acc[i][3] + bv.w;
        *(float4*)(Y + (size_t)m * 256 + nbase) = o;
    }
}

// ---------------------------------------------------------------------------
// DPP helper: row_shr accumulate term (VALU pipe, bound_ctrl=0-fill).
// ---------------------------------------------------------------------------
template<int CTRL>
__device__ __forceinline__ float dpp_term(float x) {
    return __int_as_float(
        __builtin_amdgcn_update_dpp(0, __float_as_int(x), CTRL, 0xF, 0xF, true));
}

// Sum over a 16-lane DPP row; result valid in lane 15 of each row.
__device__ __forceinline__ float row_sum_l15(float v) {
    v += dpp_term<0x111>(v);   // row_shr:1
    v += dpp_term<0x112>(v);   // row_shr:2
    v += dpp_term<0x114>(v);   // row_shr:4
    v += dpp_term<0x118>(v);   // row_shr:8
    return v;
}

// ---------------------------------------------------------------------------
// Sequential scan, v7: 1024 threads (16 waves) per batch.
//
// v6 post-mortem (R9): RA refuses to hold a 128-float/thread A fragment at
// 512 threads regardless of launch bounds (VGPR stuck at 96-104 across 3
// configs). Fix is STRUCTURAL: 16 waves -> 64 floats/thread (16 float4),
// inside the ~104-VGPR zone RA demonstrably allocates. Cap 128 declared
// via __launch_bounds__(1024, 4) (4 waves/SIMD, 1 block/CU).
//
// Decomposition: wave w owns outputs [16w,16w+16); lane (r=l>>4, c=l&15)
// computes the K-quarter [64r,64r+64) dot for output o=16w+c.
//   - NO s_partial LDS round trip: cross-K combine = shfl_xor(16) +
//     shfl_xor(32) in registers.
//   - ph2 parallel across all 16 waves: per-wave 16-output stats via a
//     4-step DPP row chain; cross-wave combine via a 128 B s_red round
//     trip (the only stats LDS traffic).
//   - State LDS in 4 padded segments (stride 68 floats): the 4 rows'
//     broadcast ds_read_b128s land on disjoint banks at compile-time
//     immediate offsets -> conflict-free, no address math in the loop.
//   - 2 raw s_barriers/step, no vmcnt drain (Bu prefetch 2 deep + global
//     stores float across barriers).
// ---------------------------------------------------------------------------
__global__ __launch_bounds__(1024, 4)
void scan_kernel(const float* __restrict__ A,     // [256,256]
                 const float* __restrict__ Bu,    // [16,4096,256]
                 const float* __restrict__ ln_g,
                 const float* __restrict__ ln_b,
                 float* __restrict__ states)      // [16,4096,256]
{
    const int b = blockIdx.x;
    const int t = threadIdx.x;
    const int w = t >> 6;        // wave 0..15 -> outputs [16w, 16w+16)
    const int l = t & 63;
    const int r = l >> 4;        // K-quarter 0..3 -> cols [64r, 64r+64)
    const int c = l & 15;
    const int o = 16 * w + c;    // this lane's output row

    // state: 4 segments of 64 floats, padded to 68 so the 4 rows'
    // simultaneous broadcast reads are bank-disjoint (68%32 gives +4
    // bank rotation per segment).
    __shared__ __align__(16) float  s4[4 * 68];
    __shared__ __align__(16) float2 s_red[16];    // per-wave (sum, sumsq)

    // --- A fragment: A[o][64r .. 64r+64) = 16 float4 = 64 VGPRs
    float4 a4[16];
    {
        const float* arow = A + (size_t)o * 256 + 64 * r;
        #pragma unroll
        for (int i = 0; i < 16; ++i)
            a4[i] = ((const float4*)arow)[i];
    }
    #pragma unroll
    for (int i = 0; i < 16; ++i)
        asm volatile("" : "+v"(a4[i].x), "+v"(a4[i].y),
                          "+v"(a4[i].z), "+v"(a4[i].w));

    const float g    = ln_g[o];
    const float beta = ln_b[o];

    const float* bu_base  = Bu + (size_t)b * S_DIM * N_DIM;
    float*       out_base = states + (size_t)b * S_DIM * N_DIM;

    float bu0 = bu_base[o];
    float bu1 = bu_base[N_DIM + o];

    if (t < 4 * 68) s4[t] = 0.0f;

    const float* sp     = s4 + 68 * r;              // this row's segment
    const int    wr_idx = 68 * (o >> 6) + (o & 63); // where y(o) lives

    __syncthreads();   // prologue only

    for (int step = 0; step < S_DIM; ++step) {
        // Bu prefetch for step+2 (no vmcnt drain in loop -> truly hidden).
        float bu2 = 0.0f;
        if (step + 2 < S_DIM)
            bu2 = bu_base[(size_t)(step + 2) * N_DIM + o];

        // --- ph1: 64-MAC partial dot over this lane's K-quarter ---
        float accA = 0.0f, accB = 0.0f;   // 2 chains: halve dep depth
        #pragma unroll
        for (int i = 0; i < 16; ++i) {
            const float4 sc = *(const float4*)(sp + 4 * i);  // bcast, imm offset
            const float4 a  = a4[i];
            if (i & 1) {
                accB = fmaf(a.x, sc.x, accB);
                accB = fmaf(a.y, sc.y, accB);
                accB = fmaf(a.z, sc.z, accB);
                accB = fmaf(a.w, sc.w, accB);
            } else {
                accA = fmaf(a.x, sc.x, accA);
                accA = fmaf(a.y, sc.y, accA);
                accA = fmaf(a.z, sc.z, accA);
                accA = fmaf(a.w, sc.w, accA);
            }
        }
        float acc = accA + accB;

        // cross-row (K-quarter) combine: all 4 dup lanes end with the
        // full 256-K dot for output o.
        acc += __shfl_xor(acc, 16, 64);   // r0<->r1, r2<->r3
        acc += __shfl_xor(acc, 32, 64);   // (r0,r1)<->(r2,r3)
        const float v = acc + bu0;

        // --- per-wave LN stats over its 16 outputs (DPP row chain) ---
        const float sv = row_sum_l15(v);
        const float sq = row_sum_l15(v * v);
        if (l == 15)                       // row 0, lane 15: one per wave
            s_red[w] = make_float2(sv, sq);

        asm volatile("s_waitcnt lgkmcnt(0)" ::: "memory");
        __builtin_amdgcn_s_barrier();

        // --- combine stats (all waves redundantly, 128 B broadcast) ---
        float sumS = 0.0f, sumQ = 0.0f;
        #pragma unroll
        for (int j = 0; j < 8; ++j) {
            const float4 p = ((const float4*)s_red)[j];  // {S,Q,S,Q}
            sumS += p.x + p.z;
            sumQ += p.y + p.w;
        }
        const float mu  = sumS * (1.0f / 256.0f);
        const float var = sumQ * (1.0f / 256.0f) - mu * mu;
        const float inv = rsqrtf(var + EPS);
        const float y   = fmaxf((v - mu) * inv * g + beta, 0.0f);

        if (r == 0) {                      // one writer per output
            s4[wr_idx] = y;
            out_base[(size_t)step * N_DIM + o] = y;   // fire & forget
        }

        asm volatile("s_waitcnt lgkmcnt(0)" ::: "memory");
        __builtin_amdgcn_s_barrier();

        bu0 = bu1;
        bu1 = bu2;
    }
}

// ---------------------------------------------------------------------------
extern "C" void kernel_launch(void* const* d_in, const int* in_sizes, int n_in,
                              void* d_out, int out_size, void* d_ws, size_t ws_size,
                              hipStream_t stream)
{
    const float* u    = (const float*)d_in[0];
    const float* A    = (const float*)d_in[1];
    const float* B_w  = (const float*)d_in[2];
    const float* B_b  = (const float*)d_in[3];
    const float* ln_g = (const float*)d_in[4];
    const float* ln_b = (const float*)d_in[5];
    const float* C_w  = (const float*)d_in[6];
    const float* C_b  = (const float*)d_in[7];

    float* states  = (float*)d_out;
    float* outputs = (float*)d_out + (size_t)B_DIM * S_DIM * N_DIM;

    // Stage Bu in the outputs region (dead until kernel 3 overwrites it).
    float* Bu = outputs;

    const int M = B_DIM * S_DIM;   // 65536

    // 1) Bu = u @ B_w^T + B_b
    {
        dim3 grid(M / 64, N_DIM / 64);
        hipLaunchKernelGGL(gemm_xwT_bias, grid, dim3(256), 0, stream,
                           u, B_w, B_b, Bu, M);
    }

    // 2) sequential scan -> states
    {
        hipLaunchKernelGGL(scan_kernel, dim3(B_DIM), dim3(1024), 0, stream,
                           A, Bu, ln_g, ln_b, states);
    }

    // 3) outputs = states @ C_w^T + C_b
    {
        dim3 grid(M / 64, N_DIM / 64);
        hipLaunchKernelGGL(gemm_xwT_bias, grid, dim3(256), 0, stream,
                           states, C_w, C_b, outputs, M);
    }
}

// Round 14
// 5712.534 us; speedup vs baseline: 1.1057x; 1.1057x over previous
//
#include <hip/hip_runtime.h>

#define B_DIM 16
#define S_DIM 4096
#define N_DIM 256
#define EPS 1e-5f

// ---------------------------------------------------------------------------
// Tiled f32 GEMM: Y[M,256] = X[M,256] @ W[256,256]^T + bias   (unchanged)
// ---------------------------------------------------------------------------
__global__ __launch_bounds__(256)
void gemm_xwT_bias(const float* __restrict__ X,
                   const float* __restrict__ W,
                   const float* __restrict__ bias,
                   float* __restrict__ Y,
                   int M)
{
    __shared__ float Xs[16][68];
    __shared__ float Ws[16][68];

    const int tid = threadIdx.x;
    const int m0 = blockIdx.x * 64;
    const int n0 = blockIdx.y * 64;
    const int tx = tid & 15;
    const int ty = tid >> 4;

    float acc[4][4] = {};

    for (int k0 = 0; k0 < 256; k0 += 16) {
        {
            const int r  = tid >> 2;
            const int kk = (tid & 3) * 4;
            float4 v = *(const float4*)(X + (size_t)(m0 + r) * 256 + k0 + kk);
            Xs[kk + 0][r] = v.x; Xs[kk + 1][r] = v.y;
            Xs[kk + 2][r] = v.z; Xs[kk + 3][r] = v.w;
            float4 w = *(const float4*)(W + (size_t)(n0 + r) * 256 + k0 + kk);
            Ws[kk + 0][r] = w.x; Ws[kk + 1][r] = w.y;
            Ws[kk + 2][r] = w.z; Ws[kk + 3][r] = w.w;
        }
        __syncthreads();

        #pragma unroll
        for (int k = 0; k < 16; ++k) {
            float4 xv = *(const float4*)&Xs[k][ty * 4];
            float4 wv = *(const float4*)&Ws[k][tx * 4];
            float xa[4] = {xv.x, xv.y, xv.z, xv.w};
            float wa[4] = {wv.x, wv.y, wv.z, wv.w};
            #pragma unroll
            for (int i = 0; i < 4; ++i)
                #pragma unroll
                for (int j = 0; j < 4; ++j)
                    acc[i][j] += xa[i] * wa[j];
        }
        __syncthreads();
    }

    const int nbase = n0 + tx * 4;
    float4 bv = *(const float4*)(bias + nbase);
    #pragma unroll
    for (int i = 0; i < 4; ++i) {
        const int m = m0 + ty * 4 + i;
        float4 o;
        o.x = acc[i][0] + bv.x;
        o.y = acc[i][1] + bv.y;
        o.z = acc[i][2] + bv.z;
        o.w = acc[i][3] + bv.w;
        *(float4*)(Y + (size_t)m * 256 + nbase) = o;
    }
}

// ---------------------------------------------------------------------------
// DPP helper: row_shr accumulate term (VALU pipe, bound_ctrl=0-fill).
// ---------------------------------------------------------------------------
template<int CTRL>
__device__ __forceinline__ float dpp_term(float x) {
    return __int_as_float(
        __builtin_amdgcn_update_dpp(0, __float_as_int(x), CTRL, 0xF, 0xF, true));
}

// Sum over a 16-lane DPP row; result valid in lane 15 of each row.
__device__ __forceinline__ float row_sum_l15(float v) {
    v += dpp_term<0x111>(v);   // row_shr:1
    v += dpp_term<0x112>(v);   // row_shr:2
    v += dpp_term<0x114>(v);   // row_shr:4
    v += dpp_term<0x118>(v);   // row_shr:8
    return v;
}

// ---------------------------------------------------------------------------
// Sequential scan, v8: 512 threads, 1 output/lane, K-halves in-wave.
//
// Evidence so far: RA never keeps a big loop-invariant A array in VGPRs
// (v4-v7: 96/104/104/52 VGPR). v6 (512 thr, ~104 VGPR, partial scratch)
// is the best-measured ph1 regime (1628 cy/step). v7's ph2 structure
// (in-wave shfl combine + distributed DPP stats) is correctness-proven
// but its 1024-thr ph1 thrashed L1 (52 VGPR, 3487 cy/step).
//
// v8 = v6's ph1 regime + v7's ph2 structure:
//   lane owns output o = 32w + (l&31); K-half h = l>>5 (128 MACs/thread,
//   same FMA wall and fragment size as v6, no pins).
//   - combine = ONE __shfl_xor(v,32)  -> no s_partial round trip at all
//   - stats distributed: DPP row_sum in every wave -> s_red[16] (128 B)
//     -> broadcast combine in all lanes (no wave0-serial phase)
//   - state reads at 128h: 2-way bank aliasing = free (m136), plain layout
//   - 2 raw s_barriers/step, no vmcnt drain, Bu prefetch 2 deep
// ---------------------------------------------------------------------------
__global__ __launch_bounds__(512)
void scan_kernel(const float* __restrict__ A,     // [256,256]
                 const float* __restrict__ Bu,    // [16,4096,256]
                 const float* __restrict__ ln_g,
                 const float* __restrict__ ln_b,
                 float* __restrict__ states)      // [16,4096,256]
{
    const int b = blockIdx.x;
    const int t = threadIdx.x;
    const int w = t >> 6;        // wave 0..7
    const int l = t & 63;
    const int h = l >> 5;        // K-half 0/1 -> cols [128h, 128h+128)
    const int c = l & 31;
    const int o = 32 * w + c;    // this lane's output row (0..255)

    __shared__ __align__(16) float  s_state[256];
    __shared__ __align__(16) float2 s_red[16];   // per 16-output group (sum, sumsq)

    // --- A fragment: A[o][128h .. 128h+128) = 32 float4 (~128 VGPR ask;
    //     RA will keep what it keeps — v6-measured equilibrium).
    float4 a4[32];
    {
        const float* arow = A + (size_t)o * 256 + 128 * h;
        #pragma unroll
        for (int i = 0; i < 32; ++i)
            a4[i] = ((const float4*)arow)[i];
    }

    const float g    = ln_g[o];
    const float beta = ln_b[o];

    const float* bu_base  = Bu + (size_t)b * S_DIM * N_DIM;
    float*       out_base = states + (size_t)b * S_DIM * N_DIM;

    float bu0 = bu_base[o];
    float bu1 = bu_base[N_DIM + o];

    if (t < 256) s_state[t] = 0.0f;

    const float4* sp = (const float4*)(s_state + 128 * h);

    __syncthreads();   // prologue only

    for (int step = 0; step < S_DIM; ++step) {
        // Bu prefetch for step+2 (no vmcnt drain in loop -> hidden).
        float bu2 = 0.0f;
        if (step + 2 < S_DIM)
            bu2 = bu_base[(size_t)(step + 2) * N_DIM + o];

        // --- ph1: 128-MAC dot over this lane's K-half (4 chains) ---
        float acc0 = 0.f, acc1 = 0.f, acc2 = 0.f, acc3 = 0.f;
        #pragma unroll
        for (int i = 0; i < 32; i += 4) {
            const float4 s0 = sp[i+0], s1 = sp[i+1], s2 = sp[i+2], s3 = sp[i+3];
            const float4 A0 = a4[i+0], A1 = a4[i+1], A2 = a4[i+2], A3 = a4[i+3];
            acc0 = fmaf(A0.w, s0.w, fmaf(A0.z, s0.z, fmaf(A0.y, s0.y, fmaf(A0.x, s0.x, acc0))));
            acc1 = fmaf(A1.w, s1.w, fmaf(A1.z, s1.z, fmaf(A1.y, s1.y, fmaf(A1.x, s1.x, acc1))));
            acc2 = fmaf(A2.w, s2.w, fmaf(A2.z, s2.z, fmaf(A2.y, s2.y, fmaf(A2.x, s2.x, acc2))));
            acc3 = fmaf(A3.w, s3.w, fmaf(A3.z, s3.z, fmaf(A3.y, s3.y, fmaf(A3.x, s3.x, acc3))));
        }
        float v = (acc0 + acc1) + (acc2 + acc3);

        // cross-half combine: lanes l and l^32 sum -> full 256-K dot.
        v += __shfl_xor(v, 32, 64);
        v += bu0;

        // --- distributed LN stats: every wave reduces its 2 rows of 16 ---
        const float sv = row_sum_l15(v);
        const float sq = row_sum_l15(v * v);
        if (l == 15 || l == 31)            // one writer per 16-output group
            s_red[2 * w + (l >> 4)] = make_float2(sv, sq);

        asm volatile("s_waitcnt lgkmcnt(0)" ::: "memory");  // s_red landed
        __builtin_amdgcn_s_barrier();

        // --- all lanes: combine 16 partials (128 B broadcast), LN, ReLU ---
        float sumS = 0.0f, sumQ = 0.0f;
        #pragma unroll
        for (int j = 0; j < 8; ++j) {
            const float4 p = ((const float4*)s_red)[j];  // {S,Q,S,Q}
            sumS += p.x + p.z;
            sumQ += p.y + p.w;
        }
        const float mu  = sumS * (1.0f / 256.0f);
        const float var = sumQ * (1.0f / 256.0f) - mu * mu;
        const float inv = rsqrtf(var + EPS);
        const float y   = fmaxf((v - mu) * inv * g + beta, 0.0f);

        if (l < 32) {                       // one writer per output
            s_state[o] = y;
            out_base[(size_t)step * N_DIM + o] = y;   // fire & forget
        }

        asm volatile("s_waitcnt lgkmcnt(0)" ::: "memory");  // state landed
        __builtin_amdgcn_s_barrier();

        bu0 = bu1;
        bu1 = bu2;
    }
}

// ---------------------------------------------------------------------------
extern "C" void kernel_launch(void* const* d_in, const int* in_sizes, int n_in,
                              void* d_out, int out_size, void* d_ws, size_t ws_size,
                              hipStream_t stream)
{
    const float* u    = (const float*)d_in[0];
    const float* A    = (const float*)d_in[1];
    const float* B_w  = (const float*)d_in[2];
    const float* B_b  = (const float*)d_in[3];
    const float* ln_g = (const float*)d_in[4];
    const float* ln_b = (const float*)d_in[5];
    const float* C_w  = (const float*)d_in[6];
    const float* C_b  = (const float*)d_in[7];

    float* states  = (float*)d_out;
    float* outputs = (float*)d_out + (size_t)B_DIM * S_DIM * N_DIM;

    // Stage Bu in the outputs region (dead until kernel 3 overwrites it).
    float* Bu = outputs;

    const int M = B_DIM * S_DIM;   // 65536

    // 1) Bu = u @ B_w^T + B_b
    {
        dim3 grid(M / 64, N_DIM / 64);
        hipLaunchKernelGGL(gemm_xwT_bias, grid, dim3(256), 0, stream,
                           u, B_w, B_b, Bu, M);
    }

    // 2) sequential scan -> states
    {
        hipLaunchKernelGGL(scan_kernel, dim3(B_DIM), dim3(512), 0, stream,
                           A, Bu, ln_g, ln_b, states);
    }

    // 3) outputs = states @ C_w^T + C_b
    {
        dim3 grid(M / 64, N_DIM / 64);
        hipLaunchKernelGGL(gemm_xwT_bias, grid, dim3(256), 0, stream,
                           states, C_w, C_b, outputs, M);
    }
}